// Round 10
// baseline (2343.160 us; speedup 1.0000x reference)
//
#include <hip/hip_runtime.h>
#include <stdint.h>

typedef unsigned long long u64;
typedef unsigned int u32;

#define NPTS    131072
#define NBATCH  16
#define NSAMP   1024
#define SUBS    16                 // blocks per batch
#define THREADS 256
#define PPT     32                 // points per thread
#define LSTRIDE 16                 // u64s per slot line: 128B -> one slot per cache line

// Packed word: [ tag:10 (bits 49..58) | key:32 (17..48) | (131071-idx):17 (0..16) ]
// key = 0 for masked-out (cand == -1), else float_bits(val)+1 (monotone for val >= 0).
// Max of packed (same tag) == reference first-max argmax (smaller index wins ties).
//
// r10 change vs r9 (cycle-model driven): each slot lives on its OWN 128B line.
// Previously all 16 publishers (16 CUs, up to 8 XCDs) stored into ONE line ->
// ~16 serialized exclusive-ownership transfers at the LLC (~1300-1900cy) gated
// the last slot's visibility, and every poll load of that line interleaved into
// the same queue. Separate lines let the 16 stores proceed through independent
// LLC banks in parallel; polls of slot i contend only with the store to slot i.
// Store count, poll count, and per-line read pressure are unchanged vs r9.
//
// Per-batch ws: 4KB = parity p at +p*2048B, slot s at +s*128B. Each slot word
// written once per round by one lane (relaxed agent store); pollers validate
// the embedded tag -> self-contained, no fences or ordering needed.

__device__ __forceinline__ u64 ld_agent(const u64* p) {
    return __hip_atomic_load(p, __ATOMIC_RELAXED, __HIP_MEMORY_SCOPE_AGENT);
}
__device__ __forceinline__ void st_agent(u64* p, u64 v) {
    __hip_atomic_store(p, v, __ATOMIC_RELAXED, __HIP_MEMORY_SCOPE_AGENT);
}

__global__ __launch_bounds__(THREADS, 1)
void fps_kernel(const float* __restrict__ x, float* __restrict__ y, u64* __restrict__ ws)
{
    const int bid   = blockIdx.x;
    const int batch = bid & (NBATCH - 1);
    const int sub   = bid >> 4;
    const int tid   = threadIdx.x;
    const int lane  = tid & 63;
    const int wv    = tid >> 6;

    const float* __restrict__ xb = x + (size_t)batch * (NPTS * 3);
    const int gbase = sub * 8192 + wv * 2048;

    // register-resident points + running min distance (static indexing only)
    float px_[PPT], py_[PPT], pz_[PPT], t_[PPT];
#pragma unroll
    for (int k = 0; k < PPT; ++k) {
        const int g = gbase + k * 64 + lane;
        const float a = xb[3 * g + 0];
        const float b = xb[3 * g + 1];
        const float c = xb[3 * g + 2];
        px_[k] = a; py_[k] = b; pz_[k] = c;
        // exactly as reference: ((a*a + b*b) + c*c), no FMA contraction
        const float mag = __fadd_rn(__fadd_rn(__fmul_rn(a, a), __fmul_rn(b, b)), __fmul_rn(c, c));
        t_[k] = (mag > 1e-3f) ? 1e10f : -1.0f;   // masked-out: cand == -1 forever
    }

    __shared__ u64 s_red[2][4];

    u64* const slots = ws + (size_t)batch * 512;   // 4KB per batch (u64 units)

    float cpx = xb[0], cpy = xb[1], cpz = xb[2];   // first pick is always index 0
    if (sub == 0 && tid == 0) {
        float* yo = y + (size_t)batch * (NSAMP * 3);
        yo[0] = cpx; yo[1] = cpy; yo[2] = cpz;
    }

    for (int it = 1; it < NSAMP; ++it) {
        // ---- update temps against current point, thread-local argmax ----
        float bv = -2.0f;
        int   bk = 0;
#pragma unroll
        for (int k = 0; k < PPT; ++k) {
            const float dx = __fsub_rn(px_[k], cpx);
            const float dy = __fsub_rn(py_[k], cpy);
            const float dz = __fsub_rn(pz_[k], cpz);
            const float d  = __fadd_rn(__fadd_rn(__fmul_rn(dx, dx), __fmul_rn(dy, dy)),
                                       __fmul_rn(dz, dz));
            const float tn = fminf(t_[k], d);
            t_[k] = tn;
            if (tn > bv) { bv = tn; bk = k; }   // strict > keeps smallest k
        }
        const int gidx = gbase + bk * 64 + lane;
        const u32 key  = (bv < 0.0f) ? 0u : (__float_as_uint(bv) + 1u);
        u64 packed = ((u64)(u32)it << 49) | ((u64)key << 17) | (u32)(131071 - gidx);

        // ---- wave reduce (max of packed, first-max tiebreak) ----
#pragma unroll
        for (int off = 32; off; off >>= 1) {
            const u64 o = __shfl_xor(packed, off);
            if (o > packed) packed = o;
        }

        const int par = it & 1;
        if (lane == 0) s_red[par][wv] = packed;   // parity-buffered: no cross-round overwrite
        __syncthreads();                          // the ONLY barrier per round

        if (wv == 0 && lane == 0) {
            u64 blk = s_red[par][0];
            if (s_red[par][1] > blk) blk = s_red[par][1];
            if (s_red[par][2] > blk) blk = s_red[par][2];
            if (s_red[par][3] > blk) blk = s_red[par][3];
            st_agent(slots + (par * SUBS + sub) * LSTRIDE, blk);   // own 128B line
        }

        // ---- all 4 waves poll the 16 slot lines independently; per-lane coord
        //      fetch overlaps straggler waiting (x read-only -> cached safe) ----
        u64   v  = 0;
        float wx = 0.0f, wy = 0.0f, wz = 0.0f;
        bool  fresh = (lane >= SUBS);
        u64*  const sp = slots + (par * SUBS + lane) * LSTRIDE;
        __builtin_amdgcn_s_sleep(4);              // ~256cy: land check#1 after visibility
        for (;;) {
            if (!fresh) {
                v = ld_agent(sp);
                if ((u32)(v >> 49) == (u32)it) {
                    fresh = true;
                    const int ci = 131071 - (int)(v & 0x1FFFF);
                    wx = xb[3 * ci + 0];          // issued as soon as THIS slot is
                    wy = xb[3 * ci + 1];          // fresh; flies while others poll
                    wz = xb[3 * ci + 2];
                }
            }
            if (__all((int)fresh)) break;
            __builtin_amdgcn_s_sleep(2);          // back off ~128cy between re-checks
        }
        // ---- reduce metas over lanes 0..15 (offsets 8..1 stay in-group) ----
#pragma unroll
        for (int off = 8; off; off >>= 1) {
            const u64 o = __shfl_xor(v, off);
            if (o > v) v = o;
        }
        const u64 win  = __shfl(v, 0);
        const int widx = 131071 - (int)(win & 0x1FFFF);
        const int wsub = widx >> 13;              // owning block (8192-pt chunks)
        cpx = __shfl(wx, wsub);                   // winner's coords already fetched
        cpy = __shfl(wy, wsub);                   //   by lane wsub during the poll
        cpz = __shfl(wz, wsub);
        if (sub == 0 && wv == 0 && lane == 0) {
            float* yo = y + ((size_t)batch * NSAMP + it) * 3;
            yo[0] = cpx; yo[1] = cpy; yo[2] = cpz;
        }
    }
}

extern "C" void kernel_launch(void* const* d_in, const int* in_sizes, int n_in,
                              void* d_out, int out_size, void* d_ws, size_t ws_size,
                              hipStream_t stream) {
    const float* x = (const float*)d_in[0];
    float* y       = (float*)d_out;
    u64* ws        = (u64*)d_ws;   // 16 batches * 4KB = 64 KiB

    // zero all slot words every call (in-graph). Tags used are 1..1023; stale
    // content (zeros, 0xAA poison, previous replay's tags overwritten here)
    // can never spuriously satisfy a round's tag check.
    hipMemsetAsync(d_ws, 0, (size_t)(NBATCH * 4096), stream);

    void* args[] = { (void*)&x, (void*)&y, (void*)&ws };
    hipLaunchCooperativeKernel((void*)fps_kernel,
                               dim3(NBATCH * SUBS), dim3(THREADS),
                               args, 0, stream);
}

// Round 11
// 1971.917 us; speedup vs baseline: 1.1883x; 1.1883x over previous
//
#include <hip/hip_runtime.h>
#include <stdint.h>

typedef unsigned long long u64;
typedef unsigned int u32;

#define NPTS    131072
#define NBATCH  16
#define NSAMP   1024
#define SUBS    16                 // blocks per batch
#define THREADS 256
#define PPT     32                 // points per thread

// Packed word: [ tag:10 (bits 49..58) | key:32 (17..48) | (131071-idx):17 (0..16) ]
// key = 0 for masked-out (cand == -1), else float_bits(val)+1 (monotone for val >= 0).
// Max of packed (same tag) == reference first-max argmax (smaller index wins ties).
//
// Layout: r9's proven one (r10's one-line-per-slot refuted: line count drives
// HBM-class traffic/latency; keep ONE 128B line per parity, coalesced polls).
// Per-batch ws: 32 u64 at stride 1024B (parity p -> slots [p*16 .. p*16+15]).
//
// r11 change vs r9: barrier-free block. The per-round __syncthreads + designated
// publisher wave (LDS RT + wake + 4-wave convoy, ~250-450cy on the critical
// chain) is replaced by last-arriving-wave publish: each wave's lane0 writes
// s_red[par][wv] then acq_rel-adds a monotonic LDS counter; the wave whose add
// returns 4*it-1 is provably last and publishes. No __syncthreads in the loop.
// Safety: a wave's round-(it+1) add follows its round-it poll -> requires this
// block's round-it publish -> requires all 4 round-it adds, so adds never
// interleave across rounds; s_red parity overwrite needs the writer to be 2
// rounds ahead, impossible while any wave still reads that parity (same
// transitive argument through the global slot polls as r7/r9).

__device__ __forceinline__ u64 ld_agent(const u64* p) {
    return __hip_atomic_load(p, __ATOMIC_RELAXED, __HIP_MEMORY_SCOPE_AGENT);
}
__device__ __forceinline__ void st_agent(u64* p, u64 v) {
    __hip_atomic_store(p, v, __ATOMIC_RELAXED, __HIP_MEMORY_SCOPE_AGENT);
}

__global__ __launch_bounds__(THREADS, 1)
void fps_kernel(const float* __restrict__ x, float* __restrict__ y, u64* __restrict__ ws)
{
    const int bid   = blockIdx.x;
    const int batch = bid & (NBATCH - 1);
    const int sub   = bid >> 4;
    const int tid   = threadIdx.x;
    const int lane  = tid & 63;
    const int wv    = tid >> 6;

    const float* __restrict__ xb = x + (size_t)batch * (NPTS * 3);
    const int gbase = sub * 8192 + wv * 2048;

    // register-resident points + running min distance (static indexing only)
    float px_[PPT], py_[PPT], pz_[PPT], t_[PPT];
#pragma unroll
    for (int k = 0; k < PPT; ++k) {
        const int g = gbase + k * 64 + lane;
        const float a = xb[3 * g + 0];
        const float b = xb[3 * g + 1];
        const float c = xb[3 * g + 2];
        px_[k] = a; py_[k] = b; pz_[k] = c;
        // exactly as reference: ((a*a + b*b) + c*c), no FMA contraction
        const float mag = __fadd_rn(__fadd_rn(__fmul_rn(a, a), __fmul_rn(b, b)), __fmul_rn(c, c));
        t_[k] = (mag > 1e-3f) ? 1e10f : -1.0f;   // masked-out: cand == -1 forever
    }

    __shared__ u64 s_red[2][4];
    __shared__ u32 s_cnt;                       // monotonic publish counter
    if (tid == 0) s_cnt = 0;
    __syncthreads();                            // once, before the round loop

    u64* const slots = ws + (size_t)batch * 128;   // 1024B per batch (u64 units)

    float cpx = xb[0], cpy = xb[1], cpz = xb[2];   // first pick is always index 0
    if (sub == 0 && tid == 0) {
        float* yo = y + (size_t)batch * (NSAMP * 3);
        yo[0] = cpx; yo[1] = cpy; yo[2] = cpz;
    }

    for (int it = 1; it < NSAMP; ++it) {
        // ---- update temps against current point, thread-local argmax ----
        float bv = -2.0f;
        int   bk = 0;
#pragma unroll
        for (int k = 0; k < PPT; ++k) {
            const float dx = __fsub_rn(px_[k], cpx);
            const float dy = __fsub_rn(py_[k], cpy);
            const float dz = __fsub_rn(pz_[k], cpz);
            const float d  = __fadd_rn(__fadd_rn(__fmul_rn(dx, dx), __fmul_rn(dy, dy)),
                                       __fmul_rn(dz, dz));
            const float tn = fminf(t_[k], d);
            t_[k] = tn;
            if (tn > bv) { bv = tn; bk = k; }   // strict > keeps smallest k
        }
        const int gidx = gbase + bk * 64 + lane;
        const u32 key  = (bv < 0.0f) ? 0u : (__float_as_uint(bv) + 1u);
        u64 packed = ((u64)(u32)it << 49) | ((u64)key << 17) | (u32)(131071 - gidx);

        // ---- wave reduce (max of packed, first-max tiebreak) ----
#pragma unroll
        for (int off = 32; off; off >>= 1) {
            const u64 o = __shfl_xor(packed, off);
            if (o > packed) packed = o;
        }

        const int par = it & 1;
        if (lane == 0) {
            s_red[par][wv] = packed;            // parity-buffered wave candidate
            // release: s_red write visible before the count; acquire: publisher's
            // s_red reads ordered after its own add
            const u32 old = __hip_atomic_fetch_add(&s_cnt, 1u, __ATOMIC_ACQ_REL,
                                                   __HIP_MEMORY_SCOPE_WORKGROUP);
            if (old == 4u * (u32)it - 1u) {     // provably the last wave this round
                u64 blk = s_red[par][0];
                if (s_red[par][1] > blk) blk = s_red[par][1];
                if (s_red[par][2] > blk) blk = s_red[par][2];
                if (s_red[par][3] > blk) blk = s_red[par][3];
                st_agent(slots + par * SUBS + sub, blk);
            }
        }

        // ---- all 4 waves poll the 16 slots independently; per-lane coord
        //      fetch overlaps straggler waiting (x read-only -> cached safe) ----
        u64   v  = 0;
        float wx = 0.0f, wy = 0.0f, wz = 0.0f;
        bool  fresh = (lane >= SUBS);
        u64*  const sp = slots + par * SUBS + lane;
        __builtin_amdgcn_s_sleep(8);            // ~512cy: land check#1 after visibility
        for (;;) {
            if (!fresh) {
                v = ld_agent(sp);
                if ((u32)(v >> 49) == (u32)it) {
                    fresh = true;
                    const int ci = 131071 - (int)(v & 0x1FFFF);
                    wx = xb[3 * ci + 0];        // issued as soon as THIS slot is
                    wy = xb[3 * ci + 1];        // fresh; flies while others poll
                    wz = xb[3 * ci + 2];
                }
            }
            if (__all((int)fresh)) break;
            __builtin_amdgcn_s_sleep(2);        // back off ~128cy between re-checks
        }
        // ---- reduce metas over lanes 0..15 (offsets 8..1 stay in-group) ----
#pragma unroll
        for (int off = 8; off; off >>= 1) {
            const u64 o = __shfl_xor(v, off);
            if (o > v) v = o;
        }
        const u64 win  = __shfl(v, 0);
        const int widx = 131071 - (int)(win & 0x1FFFF);
        const int wsub = widx >> 13;            // owning block (8192-pt chunks)
        cpx = __shfl(wx, wsub);                 // winner's coords already fetched
        cpy = __shfl(wy, wsub);                 //   by lane wsub during the poll
        cpz = __shfl(wz, wsub);
        if (sub == 0 && wv == 0 && lane == 0) {
            float* yo = y + ((size_t)batch * NSAMP + it) * 3;
            yo[0] = cpx; yo[1] = cpy; yo[2] = cpz;
        }
    }
}

extern "C" void kernel_launch(void* const* d_in, const int* in_sizes, int n_in,
                              void* d_out, int out_size, void* d_ws, size_t ws_size,
                              hipStream_t stream) {
    const float* x = (const float*)d_in[0];
    float* y       = (float*)d_out;
    u64* ws        = (u64*)d_ws;   // 16 batches * 1024B = 16 KiB

    // zero all slot words every call (in-graph). Tags used are 1..1023; stale
    // content (zeros, 0xAA poison, previous replay's tags overwritten here)
    // can never spuriously satisfy a round's tag check.
    hipMemsetAsync(d_ws, 0, (size_t)(NBATCH * 1024), stream);

    void* args[] = { (void*)&x, (void*)&y, (void*)&ws };
    hipLaunchCooperativeKernel((void*)fps_kernel,
                               dim3(NBATCH * SUBS), dim3(THREADS),
                               args, 0, stream);
}